// Round 1
// baseline (341.717 us; speedup 1.0000x reference)
//
#include <hip/hip_runtime.h>
#include <hip/hip_bf16.h>

constexpr int B = 4, L = 256, D = 256;
constexpr int RS = 288, PADC = 16;            // padded row stride / col offset
constexpr size_t SZ  = (size_t)B * L * D;     // 262144
constexpr size_t SZP = (size_t)B * L * RS;    // 294912

// workspace offsets (floats)
constexpr size_t OFF_E1   = 0;
constexpr size_t OFF_E2   = OFF_E1 + SZ;
constexpr size_t OFF_Q    = OFF_E2 + SZ;
constexpr size_t OFF_KT   = OFF_Q + SZ;
constexpr size_t OFF_S    = OFF_KT + SZ;
constexpr size_t OFF_STN  = OFF_S + SZ;
constexpr size_t OFF_TMPA = OFF_STN + SZ;           // 2 proteins padded
constexpr size_t OFF_TMPB = OFF_TMPA + 2 * SZP;
constexpr size_t OFF_PART = OFF_TMPB + 2 * SZP;     // 2 proteins * 2 isplit * SZ
constexpr size_t OFF_BS   = OFF_PART + 4 * SZ;      // 256
constexpr size_t OFF_SUM  = OFF_BS + 256;           // 4
constexpr size_t OFF_PP   = OFF_SUM + 4;            // 4*16*4*256 = 65536
constexpr size_t OFF_POOL = OFF_PP + 65536;         // 1024
constexpr size_t OFF_H    = OFF_POOL + 1024;        // 8192
constexpr size_t OFF_F1P  = OFF_H + 8192;           // 8*4*600 = 19200
constexpr size_t OFF_H1   = OFF_F1P + 19200;        // 2400
constexpr size_t OFF_H2   = OFF_H1 + 2400;          // 1200

__device__ __forceinline__ float tanh_fast(float x) {
  float e = __expf(2.0f * x);
  return 1.0f - __fdividef(2.0f, e + 1.0f);
}
__device__ __forceinline__ float sig_fast(float x) {
  return __fdividef(1.0f, 1.0f + __expf(-x));
}
__device__ __forceinline__ float lrelu(float x) { return x >= 0.0f ? x : 0.1f * x; }

// ---------------- embedding ----------------
__global__ __launch_bounds__(256) void k_embed(const int* __restrict__ t1,
                                               const int* __restrict__ t2,
                                               const float* __restrict__ emb,
                                               float* __restrict__ ws) {
  int blk = blockIdx.x;                 // p(1) b(2) l(8)
  int l = blk & 255, b = (blk >> 8) & 3, p = blk >> 10;
  const int* tok = p ? t2 : t1;
  int tv = tok[b * L + l];
  float* dst = ws + OFF_TMPA + (size_t)p * SZP + (size_t)(b * L + l) * RS + PADC;
  dst[threadIdx.x] = emb[(size_t)tv * D + threadIdx.x];
}

// ---------------- conv partial (both proteins, 2-way i-split) ----------------
template <int K>
__global__ __launch_bounds__(256) void k_conv_partial(const float* __restrict__ ws_in,
                                                      const float* __restrict__ w,
                                                      float* __restrict__ part,
                                                      int pad_lo) {
  int blk = blockIdx.x;                 // p(1) b(2) oc(6) is(1)
  int is = blk & 1, oc = (blk >> 1) & 63, b = (blk >> 7) & 3, p = blk >> 9;
  int j = threadIdx.x;
  int o0 = oc * 4;
  const float* inb = ws_in + (size_t)p * SZP + (size_t)(b * L + is * 128) * RS + PADC - pad_lo + j;
  const float* wp = w + ((size_t)o0 * D + (size_t)is * 128) * K;
  float a0 = 0.f, a1 = 0.f, a2 = 0.f, a3 = 0.f;
#pragma unroll 2
  for (int ii = 0; ii < 128; ++ii) {
    float v[K];
#pragma unroll
    for (int k = 0; k < K; ++k) v[k] = inb[(size_t)ii * RS + k];
    const float* w0 = wp + (size_t)ii * K;
#pragma unroll
    for (int k = 0; k < K; ++k) {
      a0 = fmaf(w0[k], v[k], a0);
      a1 = fmaf(w0[(size_t)D * K + k], v[k], a1);
      a2 = fmaf(w0[(size_t)2 * D * K + k], v[k], a2);
      a3 = fmaf(w0[(size_t)3 * D * K + k], v[k], a3);
    }
  }
  float* pp = part + (((size_t)(p * 2 + is) * B + b) * L + o0) * D + j;
  pp[0] = a0; pp[D] = a1; pp[2 * D] = a2; pp[3 * D] = a3;
}

// ---------------- conv combine: sum partials + bias + relu ----------------
__global__ __launch_bounds__(256) void k_conv_combine(const float* __restrict__ part,
                                                      const float* __restrict__ bias,
                                                      float* __restrict__ out,
                                                      int out_rs, int out_pad,
                                                      size_t out_pstride) {
  size_t idx = (size_t)blockIdx.x * 256 + threadIdx.x;   // p(1) b(2) o(8) j(8)
  int j = idx & 255, o = (idx >> 8) & 255, b = (idx >> 16) & 3, p = (int)(idx >> 18);
  float s = part[(((size_t)(p * 2 + 0) * B + b) * L + o) * D + j] +
            part[(((size_t)(p * 2 + 1) * B + b) * L + o) * D + j] + bias[o];
  s = fmaxf(s, 0.0f);
  out[(size_t)p * out_pstride + (size_t)(b * L + o) * out_rs + out_pad + j] = s;
}

// ---------------- joint-attention projections: q and k^T ----------------
__global__ __launch_bounds__(256) void k_ja(const float* __restrict__ e_base,
                                            const float* __restrict__ w1,
                                            const float* __restrict__ b1,
                                            const float* __restrict__ w2,
                                            const float* __restrict__ b2,
                                            float* __restrict__ q,
                                            float* __restrict__ kT) {
  int blk = blockIdx.x;                 // p(1) b(2) it(6)
  int it = blk & 63, b = (blk >> 6) & 3, p = blk >> 8;
  int n = threadIdx.x, i0 = it * 4;
  const float* e = e_base + (size_t)p * SZ + (size_t)(b * L + i0) * D;
  const float* W = p ? w2 : w1;
  float bias = (p ? b2 : b1)[n];
  float a0 = bias, a1 = bias, a2 = bias, a3 = bias;
  for (int d = 0; d < D; ++d) {
    float wv = W[(size_t)d * D + n];
    a0 = fmaf(e[d], wv, a0);
    a1 = fmaf(e[D + d], wv, a1);
    a2 = fmaf(e[2 * D + d], wv, a2);
    a3 = fmaf(e[3 * D + d], wv, a3);
  }
  if (p == 0) {
    float* qp = q + (size_t)(b * L + i0) * D + n;
    qp[0] = a0; qp[D] = a1; qp[2 * D] = a2; qp[3 * D] = a3;
  } else {
    float4 v = make_float4(a0, a1, a2, a3);
    *(float4*)(kT + (size_t)(b * L + n) * D + i0) = v;
  }
}

// ---------------- scores: sigmoid(q k^T) + block partial sums ----------------
__global__ __launch_bounds__(256) void k_scores(const float* __restrict__ q,
                                                const float* __restrict__ kT,
                                                float* __restrict__ S,
                                                float* __restrict__ bsums) {
  int blk = blockIdx.x;                 // b(2) it(6)
  int it = blk & 63, b = blk >> 6;
  int k = threadIdx.x, i0 = it * 4;
  const float* qb = q + (size_t)(b * L + i0) * D;
  const float* kTb = kT + (size_t)b * L * D + k;
  float a0 = 0.f, a1 = 0.f, a2 = 0.f, a3 = 0.f;
  for (int n = 0; n < D; ++n) {
    float kv = kTb[(size_t)n * D];
    a0 = fmaf(qb[n], kv, a0);
    a1 = fmaf(qb[D + n], kv, a1);
    a2 = fmaf(qb[2 * D + n], kv, a2);
    a3 = fmaf(qb[3 * D + n], kv, a3);
  }
  float s0 = sig_fast(a0), s1 = sig_fast(a1), s2 = sig_fast(a2), s3 = sig_fast(a3);
  float* Sp = S + (size_t)(b * L + i0) * D + k;
  Sp[0] = s0; Sp[D] = s1; Sp[2 * D] = s2; Sp[3 * D] = s3;
  __shared__ float red[256];
  red[k] = s0 + s1 + s2 + s3;
  __syncthreads();
  for (int st = 128; st > 0; st >>= 1) {
    if (k < st) red[k] += red[k + st];
    __syncthreads();
  }
  if (k == 0) bsums[blk] = red[0];
}

__global__ __launch_bounds__(256) void k_sumreduce(const float* __restrict__ bsums,
                                                   float* __restrict__ sums) {
  int t = threadIdx.x, b = t >> 6, l = t & 63;
  float v = bsums[b * 64 + l];
  for (int off = 32; off; off >>= 1) v += __shfl_down(v, off, 64);
  if (l == 0) sums[b] = v;
}

// ---------------- normalize + write inter output + transposed copy ----------------
__global__ __launch_bounds__(256) void k_norm_t(const float* __restrict__ S,
                                                const float* __restrict__ sums,
                                                float* __restrict__ inter_out,
                                                float* __restrict__ STn) {
  int blk = blockIdx.x;                 // b(2) ti(2) tk(2)
  int tk = blk & 3, ti = (blk >> 2) & 3, b = blk >> 4;
  int i0 = ti * 64, k0 = tk * 64;
  float inv = 1.0f / sums[b];
  __shared__ float lds[64][65];
  int c = threadIdx.x & 63, rq = threadIdx.x >> 6;
#pragma unroll
  for (int ps = 0; ps < 16; ++ps) {
    int r = ps * 4 + rq;
    float v = S[(size_t)(b * L + i0 + r) * D + k0 + c] * inv;
    inter_out[(size_t)(b * L + i0 + r) * D + k0 + c] = v;
    lds[r][c] = v;
  }
  __syncthreads();
#pragma unroll
  for (int ps = 0; ps < 16; ++ps) {
    int r = ps * 4 + rq;                // local k index
    STn[(size_t)(b * L + k0 + r) * D + i0 + c] = lds[c][r];
  }
}

// ---------------- bilinear tanh pooling ----------------
__global__ __launch_bounds__(256) void k_pool(const float* __restrict__ e1,
                                              const float* __restrict__ e2,
                                              const float* __restrict__ STn,
                                              float* __restrict__ pp) {
  int blk = blockIdx.x;                 // b(2) ich(4) kch(2)
  int kch = blk & 3, ich = (blk >> 2) & 15, b = blk >> 6;
  int d = threadIdx.x, i0 = ich * 16, k0 = kch * 64;
  float ev[16];
#pragma unroll
  for (int ii = 0; ii < 16; ++ii) ev[ii] = e1[(size_t)(b * L + i0 + ii) * D + d];
  float acc = 0.f;
  for (int k = k0; k < k0 + 64; ++k) {
    float e2v = e2[(size_t)(b * L + k) * D + d];
    const float* sp = STn + (size_t)(b * L + k) * D + i0;
#pragma unroll
    for (int ii = 0; ii < 16; ++ii)
      acc = fmaf(tanh_fast(ev[ii] * e2v), sp[ii], acc);
  }
  pp[(((size_t)b * 16 + ich) * 4 + kch) * D + d] = acc;
}

__global__ __launch_bounds__(256) void k_poolcomb(const float* __restrict__ pp,
                                                  float* __restrict__ pooled) {
  int b = blockIdx.x, d = threadIdx.x;
  float s = 0.f;
  for (int m = 0; m < 64; ++m) s += pp[((size_t)b * 64 + m) * D + d];
  pooled[b * D + d] = s;
}

// ---------------- head: conv(stride2) + lrelu + maxpool4 ----------------
__global__ __launch_bounds__(256) void k_head1(const float* __restrict__ pooled,
                                               const float* __restrict__ rcw,
                                               const float* __restrict__ rcb,
                                               float* __restrict__ h) {
  int t = threadIdx.x, b = t >> 6, c = t & 63;
  float w0 = rcw[c * 4 + 0], w1 = rcw[c * 4 + 1], w2 = rcw[c * 4 + 2], w3 = rcw[c * 4 + 3];
  float bias = rcb[c];
  const float* pb = pooled + b * D;
  for (int m = 0; m < 32; ++m) {
    float mx = -1e30f;
#pragma unroll
    for (int r = 0; r < 4; ++r) {
      int p = 4 * m + r;
      int base = 2 * p - 1;
      float y = bias;
      if (base >= 0) y = fmaf(w0, pb[base], y);
      y = fmaf(w1, pb[base + 1], y);
      y = fmaf(w2, pb[base + 2], y);
      if (base + 3 < 256) y = fmaf(w3, pb[base + 3], y);
      y = lrelu(y);
      mx = fmaxf(mx, y);
    }
    h[(size_t)(b * 64 + c) * 32 + m] = mx;
  }
}

// ---------------- fc1 (i-split partials) ----------------
__global__ __launch_bounds__(256) void k_fc1(const float* __restrict__ h,
                                             const float* __restrict__ w,
                                             float* __restrict__ f1p) {
  int blk = blockIdx.x;
  int ot = blk % 10, ich = blk / 10;
  int t = threadIdx.x, o = ot * 64 + (t & 63), b = t >> 6;
  if (o >= 600) return;
  float acc = 0.f;
  const float* hb = h + (size_t)b * 2048 + (size_t)ich * 256;
  const float* wb = w + (size_t)ich * 256 * 600 + o;
  for (int i = 0; i < 256; ++i) acc = fmaf(hb[i], wb[(size_t)i * 600], acc);
  f1p[((size_t)ich * 4 + b) * 600 + o] = acc;
}

__global__ __launch_bounds__(256) void k_fc1c(const float* __restrict__ f1p,
                                              const float* __restrict__ bias,
                                              float* __restrict__ h1) {
  int idx = blockIdx.x * 256 + threadIdx.x;
  if (idx >= 2400) return;
  int o = idx % 600, b = idx / 600;
  float s = bias[o];
#pragma unroll
  for (int ich = 0; ich < 8; ++ich) s += f1p[((size_t)ich * 4 + b) * 600 + o];
  h1[(size_t)b * 600 + o] = lrelu(s);
}

__global__ __launch_bounds__(256) void k_fc2(const float* __restrict__ h1,
                                             const float* __restrict__ w,
                                             const float* __restrict__ bias,
                                             float* __restrict__ h2) {
  int idx = blockIdx.x * 256 + threadIdx.x;
  if (idx >= 1200) return;
  int o = idx % 300, b = idx / 300;
  float s = bias[o];
  const float* hb = h1 + (size_t)b * 600;
  for (int i = 0; i < 600; ++i) s = fmaf(hb[i], w[(size_t)i * 300 + o], s);
  h2[(size_t)b * 300 + o] = lrelu(s);
}

__global__ __launch_bounds__(256) void k_fc3(const float* __restrict__ h2,
                                             const float* __restrict__ w,
                                             const float* __restrict__ bias,
                                             float* __restrict__ out) {
  int t = threadIdx.x, b = t >> 6, l = t & 63;
  float s = 0.f;
#pragma unroll
  for (int m = 0; m < 5; ++m) {
    int i = l + m * 64;
    if (i < 300) s = fmaf(h2[(size_t)b * 300 + i], w[i], s);
  }
  for (int off = 32; off; off >>= 1) s += __shfl_down(s, off, 64);
  if (l == 0) out[262144 + b] = s + bias[0];
}

extern "C" void kernel_launch(void* const* d_in, const int* in_sizes, int n_in,
                              void* d_out, int out_size, void* d_ws, size_t ws_size,
                              hipStream_t stream) {
  float* ws = (float*)d_ws;
  const int* p1 = (const int*)d_in[0];
  const int* p2 = (const int*)d_in[1];
  const float* emb  = (const float*)d_in[2];
  const float* w0   = (const float*)d_in[3];
  const float* b0   = (const float*)d_in[4];
  const float* w1   = (const float*)d_in[5];
  const float* b1   = (const float*)d_in[6];
  const float* w2   = (const float*)d_in[7];
  const float* b2   = (const float*)d_in[8];
  const float* ja1w = (const float*)d_in[9];
  const float* ja1b = (const float*)d_in[10];
  const float* ja2w = (const float*)d_in[11];
  const float* ja2b = (const float*)d_in[12];
  const float* rcw  = (const float*)d_in[13];
  const float* rcb  = (const float*)d_in[14];
  const float* fc1w = (const float*)d_in[15];
  const float* fc1b = (const float*)d_in[16];
  const float* fc2w = (const float*)d_in[17];
  const float* fc2b = (const float*)d_in[18];
  const float* fc3w = (const float*)d_in[19];
  const float* fc3b = (const float*)d_in[20];
  float* out = (float*)d_out;

  // zero padded staging buffers (margins must be 0)
  hipMemsetAsync(ws + OFF_TMPA, 0, sizeof(float) * 4 * SZP, stream);

  k_embed<<<2048, 256, 0, stream>>>(p1, p2, emb, ws);

  k_conv_partial<4><<<1024, 256, 0, stream>>>(ws + OFF_TMPA, w0, ws + OFF_PART, 1);
  k_conv_combine<<<2048, 256, 0, stream>>>(ws + OFF_PART, b0, ws + OFF_TMPB, RS, PADC, SZP);
  k_conv_partial<8><<<1024, 256, 0, stream>>>(ws + OFF_TMPB, w1, ws + OFF_PART, 3);
  k_conv_combine<<<2048, 256, 0, stream>>>(ws + OFF_PART, b1, ws + OFF_TMPA, RS, PADC, SZP);
  k_conv_partial<12><<<1024, 256, 0, stream>>>(ws + OFF_TMPA, w2, ws + OFF_PART, 5);
  k_conv_combine<<<2048, 256, 0, stream>>>(ws + OFF_PART, b2, ws + OFF_E1, D, 0, SZ);

  k_ja<<<512, 256, 0, stream>>>(ws + OFF_E1, ja1w, ja1b, ja2w, ja2b, ws + OFF_Q, ws + OFF_KT);
  k_scores<<<256, 256, 0, stream>>>(ws + OFF_Q, ws + OFF_KT, ws + OFF_S, ws + OFF_BS);
  k_sumreduce<<<1, 256, 0, stream>>>(ws + OFF_BS, ws + OFF_SUM);
  k_norm_t<<<64, 256, 0, stream>>>(ws + OFF_S, ws + OFF_SUM, out, ws + OFF_STN);

  k_pool<<<256, 256, 0, stream>>>(ws + OFF_E1, ws + OFF_E2, ws + OFF_STN, ws + OFF_PP);
  k_poolcomb<<<4, 256, 0, stream>>>(ws + OFF_PP, ws + OFF_POOL);

  k_head1<<<1, 256, 0, stream>>>(ws + OFF_POOL, rcw, rcb, ws + OFF_H);
  k_fc1<<<80, 256, 0, stream>>>(ws + OFF_H, fc1w, ws + OFF_F1P);
  k_fc1c<<<10, 256, 0, stream>>>(ws + OFF_F1P, fc1b, ws + OFF_H1);
  k_fc2<<<5, 256, 0, stream>>>(ws + OFF_H1, fc2w, fc2b, ws + OFF_H2);
  k_fc3<<<1, 256, 0, stream>>>(ws + OFF_H2, fc3w, fc3b, out);
}